// Round 4
// baseline (287.905 us; speedup 1.0000x reference)
//
#include <hip/hip_runtime.h>

#define NPTS  32768
#define DIM   256

#define ZQ_OFF   0
#define LOSS_OFF 8388608
#define IDX_OFF  8388609

typedef __attribute__((ext_vector_type(8))) short short8;
typedef __attribute__((ext_vector_type(4))) float f32x4;
typedef unsigned short ushort_t;
typedef unsigned int u32;
typedef unsigned long long u64;

// z layout [B, D, H, W]: point n = b*1024 + h*32 + w ; elem (n,d) at b*262144 + d*1024 + hw
__device__ __forceinline__ int z_base(int n) { return ((n >> 10) << 18) | (n & 1023); }

// RNE float->bf16 (bits)
__device__ __forceinline__ ushort_t f2bf(float f) {
    u32 u = __float_as_uint(f);
    u += 0x7FFFu + ((u >> 16) & 1u);
    return (ushort_t)(u >> 16);
}

__device__ __forceinline__ u64 pack_vi(float v, int i) {
    u32 u = __float_as_uint(v);
    u32 key = (u & 0x80000000u) ? ~u : u;   // monotone float->uint (finite)
    return ((u64)key << 32) | (u32)i;
}

// ---- numpy pairwise sum (AVX512 npyv order) of squares, 128 elems ----
__device__ __forceinline__ float np_half_sq(const float* __restrict__ p, int stride) {
    float S[16];
#pragma unroll
    for (int l = 0; l < 16; ++l) {
        float t[8];
#pragma unroll
        for (int j = 0; j < 8; ++j) {
            float v = p[(j * 16 + l) * stride];
            t[j] = __fmul_rn(v, v);
        }
        S[l] = __fadd_rn(__fadd_rn(__fadd_rn(t[0], t[1]), __fadd_rn(t[2], t[3])),
                         __fadd_rn(__fadd_rn(t[4], t[5]), __fadd_rn(t[6], t[7])));
    }
    float u[8];
#pragma unroll
    for (int i = 0; i < 8; ++i) u[i] = __fadd_rn(S[i], S[i + 8]);
    float v4[4];
#pragma unroll
    for (int i = 0; i < 4; ++i) v4[i] = __fadd_rn(u[i], u[i + 4]);
    return __fadd_rn(__fadd_rn(v4[0], v4[2]), __fadd_rn(v4[1], v4[3]));
}
__device__ __forceinline__ float np_sum256_sq(const float* __restrict__ p, int stride) {
    return __fadd_rn(np_half_sq(p, stride), np_half_sq(p + 128 * stride, stride));
}

// same square chain (bit-identical z2), abs-sum fused into the same pass (order-free bound input)
__device__ __forceinline__ float np_half_sq_abs(const float* __restrict__ p, int stride, float* aacc) {
    float S[16]; float a = *aacc;
#pragma unroll
    for (int l = 0; l < 16; ++l) {
        float t[8];
#pragma unroll
        for (int j = 0; j < 8; ++j) {
            float v = p[(j * 16 + l) * stride];
            t[j] = __fmul_rn(v, v);
            a = __fadd_rn(a, fabsf(v));
        }
        S[l] = __fadd_rn(__fadd_rn(__fadd_rn(t[0], t[1]), __fadd_rn(t[2], t[3])),
                         __fadd_rn(__fadd_rn(t[4], t[5]), __fadd_rn(t[6], t[7])));
    }
    float u[8];
#pragma unroll
    for (int i = 0; i < 8; ++i) u[i] = __fadd_rn(S[i], S[i + 8]);
    float v4[4];
#pragma unroll
    for (int i = 0; i < 4; ++i) v4[i] = __fadd_rn(u[i], u[i + 4]);
    *aacc = a;
    return __fadd_rn(__fadd_rn(v4[0], v4[2]), __fadd_rn(v4[1], v4[3]));
}

// blocks 0..127: per-point z2 (np order) + fused abs-sum -> eps + bestG init (single z pass).
// blocks 128..143: e2/e2h + XOR-swizzled kt-tile bf16 image of emb (64 rows per block):
//   tile kt (0..31) = 16KB covering k in [kt*32,+32), ALL 256 d.
//   within tile, byte (r*512 + c16*16), r=k&31, holds bf16 emb[kt*32+r][dslot*8..+7],
//   dslot = c16 ^ (r&7)   (bank swizzle baked in).
__global__ __launch_bounds__(256) void setup_kernel(
    const float* __restrict__ z, const float* __restrict__ emb,
    float* __restrict__ z2, float* __restrict__ eps,
    float* __restrict__ e2, float* __restrict__ e2h,
    ushort_t* __restrict__ ebf, u64* __restrict__ bestG,
    double* __restrict__ loss_acc, unsigned int* __restrict__ ticket)
{
    if (blockIdx.x < 128) {
        int n = blockIdx.x * 256 + threadIdx.x;
        const float* p = z + z_base(n);
        float a = 0.0f;
        float h0 = np_half_sq_abs(p, 1024, &a);
        float h1 = np_half_sq_abs(p + 128 * 1024, 1024, &a);
        z2[n] = __fadd_rn(h0, h1);
        eps[n] = __builtin_fmaf(1e-5f, a, 3e-4f);   // sound |d~ - d| bound
        bestG[n] = 0x7FFFFFFFFFFFFFFFULL;
        if (blockIdx.x == 0 && threadIdx.x == 0) { *loss_acc = 0.0; *ticket = 0u; }
    } else {
        int kb = (blockIdx.x - 128) * 64;            // 64 emb rows per block
        for (int i = threadIdx.x; i < 2048; i += 256) {
            int klocal = i >> 5, c16 = i & 31;
            int k = kb + klocal;
            int r = k & 31, ktc = k >> 5;
            int dslot = c16 ^ (r & 7);
            const float* e = emb + k * 256 + dslot * 8;
            short8 ov;
#pragma unroll
            for (int j = 0; j < 8; ++j) ov[j] = (short)f2bf(e[j]);
            *(short8*)(ebf + ktc * 8192 + r * 256 + c16 * 8) = ov;
        }
        if (threadIdx.x < 64) {
            int k = kb + threadIdx.x;
            float s = np_sum256_sq(emb + k * DIM, 1);
            e2[k] = s;
            e2h[k] = 0.5f * s;
        }
    }
}

// ---------------- MFMA distance + candidate filter + exact recheck ----------------
// grid 2048: block = 64 pts x 256 k (K quarter kq = bid&3, points nblk = bid>>2).
// 4 waves each own 16 POINTS (mt=1). A hoisted to 32 VGPRs. es = block-shared 32-k full-d
// tile (16KB), double-buffered, linear global_load_lds; one __syncthreads per kt.
// Per-quarter running-max threshold (superset of global-threshold candidates -> sound).
// Winner via global atomicMin on packed (dist,k): exact argmin semantics preserved.
#define ZS_STRIDE 264

__device__ __forceinline__ void async_cp16(const ushort_t* g, ushort_t* l) {
    __builtin_amdgcn_global_load_lds(
        (const __attribute__((address_space(1))) u32*)g,
        (__attribute__((address_space(3))) u32*)l, 16, 0, 0);
}

__global__ __launch_bounds__(256, 4) void dist_kernel(
    const float* __restrict__ z, const float* __restrict__ emb,
    const ushort_t* __restrict__ ebf,
    const float* __restrict__ z2w, const float* __restrict__ e2w,
    const float* __restrict__ e2hw, const float* __restrict__ epsw,
    u64* __restrict__ bestG)
{
    // uni: zs [64][264] bf16 transient (33792B) UNION es 2x16KB (32768B) UNION zx 32x68 f32
    __shared__ __align__(16) short uni[16896];
    __shared__ __align__(16) int cl[1024];      // 64 pts x 16 slots
    __shared__ float e2hS[256];
    __shared__ float epsS[64], z2S[64];
    __shared__ unsigned int cntS[64];
    __shared__ int ovfS;

    const int tid = threadIdx.x;
    const int w  = tid >> 6;       // wave 0..3
    const int l  = tid & 63;
    const int lq = l >> 4;
    const int lr = l & 15;
    const int kq = blockIdx.x & 3;           // K quarter
    const int n0 = (blockIdx.x >> 2) << 6;   // point base
    const int zb = z_base(n0);
    const int pbase = w << 4;                // wave's 16-point base
    const int ktg0 = kq << 3;                // first global 32-k tile of this quarter

    if (tid < 64) {
        cntS[tid] = 0u;
        epsS[tid] = epsw[n0 + tid]; z2S[tid] = z2w[n0 + tid];
    }
    if (tid == 0) ovfS = 0;
    e2hS[tid] = e2hw[(kq << 8) + tid];

    // stage zs (fp32 -> bf16, transpose to [pt][d]); transient
    {
        short* zs = uni;
        int q = tid & 15, d0 = tid >> 4;
#pragma unroll 4
        for (int i = 0; i < 16; ++i) {
            int d = d0 + 16 * i;
            float4 v = *(const float4*)(z + zb + (d << 10) + 4 * q);
            zs[(4 * q + 0) * ZS_STRIDE + d] = (short)f2bf(v.x);
            zs[(4 * q + 1) * ZS_STRIDE + d] = (short)f2bf(v.y);
            zs[(4 * q + 2) * ZS_STRIDE + d] = (short)f2bf(v.z);
            zs[(4 * q + 3) * ZS_STRIDE + d] = (short)f2bf(v.w);
        }
    }
    __syncthreads();

    // hoist A-fragments: wave w's 16 points, 8 d-chunks -> 32 VGPRs
    short8 af[8];
#pragma unroll
    for (int d8 = 0; d8 < 8; ++d8)
        af[d8] = *(const short8*)(uni + (pbase + lr) * ZS_STRIDE + d8 * 32 + lq * 8);

    // per-lane filter state for the 4 points (lq*4+r) this lane owns in the C layout
    float eps_r[4], Mr[4];
#pragma unroll
    for (int r = 0; r < 4; ++r) {
        eps_r[r] = epsS[pbase + lq * 4 + r];
        Mr[r] = -3.4e38f;
    }
    __syncthreads();   // all af reads done; zs region now reusable as es

    // prologue: stage tile ktg0 into buf0 (wave w copies 4KB linearly)
    {
        const ushort_t* gs = ebf + ktg0 * 8192 + w * 2048 + (l << 3);
        ushort_t* ld = (ushort_t*)uni + w * 2048;
        async_cp16(gs,        ld);
        async_cp16(gs +  512, ld +  512);
        async_cp16(gs + 1024, ld + 1024);
        async_cp16(gs + 1536, ld + 1536);
    }

    f32x4 acc[2];
#pragma unroll
    for (int nt = 0; nt < 2; ++nt) {
        float e = e2hS[16 * nt + lr];
        f32x4 iv = { -e, -e, -e, -e };
        acc[nt] = iv;
    }
    __syncthreads();   // drains vmcnt -> tile 0 ready for all waves

#pragma unroll 1
    for (int kt = 0; kt < 8; ++kt) {
        if (kt < 7) {   // stage kt+1 into the other buffer
            const ushort_t* gs = ebf + (ktg0 + kt + 1) * 8192 + w * 2048 + (l << 3);
            ushort_t* ld = (ushort_t*)uni + (((kt + 1) & 1) << 13) + w * 2048;
            async_cp16(gs,        ld);
            async_cp16(gs +  512, ld +  512);
            async_cp16(gs + 1024, ld + 1024);
            async_cp16(gs + 1536, ld + 1536);
        }
        const short* esb = uni + ((kt & 1) << 13);
#pragma unroll
        for (int dt = 0; dt < 8; ++dt) {
            const int c16s = (((dt << 2) + lq) ^ (lr & 7)) << 3;   // short offset
            short8 b0 = *(const short8*)(esb + (lr)      * 256 + c16s);
            short8 b1 = *(const short8*)(esb + (16 + lr) * 256 + c16s);
            acc[0] = __builtin_amdgcn_mfma_f32_16x16x32_bf16(af[dt], b0, acc[0], 0, 0, 0);
            acc[1] = __builtin_amdgcn_mfma_f32_16x16x32_bf16(af[dt], b1, acc[1], 0, 0, 0);
        }
        // ---- filter: per-point running max + candidate record (register-only) ----
        {
            float mx[4];
#pragma unroll
            for (int r = 0; r < 4; ++r) mx[r] = fmaxf(acc[0][r], acc[1][r]);
#pragma unroll
            for (int s = 1; s <= 8; s <<= 1)
#pragma unroll
                for (int r = 0; r < 4; ++r)
                    mx[r] = fmaxf(mx[r], __shfl_xor(mx[r], s, 64));   // reduce over lr
            float thr[4];
#pragma unroll
            for (int r = 0; r < 4; ++r) {
                Mr[r] = fmaxf(Mr[r], mx[r]);
                thr[r] = Mr[r] - eps_r[r];   // local thr <= global thr -> superset, sound
            }
#pragma unroll
            for (int nt = 0; nt < 2; ++nt)
#pragma unroll
                for (int r = 0; r < 4; ++r) {
                    if (acc[nt][r] >= thr[r]) {
                        int p = pbase + lq * 4 + r;
                        int kk = ((ktg0 + kt) << 5) + 16 * nt + lr;
                        unsigned int pos = atomicAdd(&cntS[p], 1u);
                        if (pos < 16u) cl[p * 16 + pos] = kk;
                        else atomicMax(&ovfS, 1);
                    }
                }
        }
        if (kt < 7) {   // re-init acc = -e2/2 for next tile
#pragma unroll
            for (int nt = 0; nt < 2; ++nt) {
                float e = e2hS[(kt + 1) * 32 + 16 * nt + lr];
                f32x4 iv = { -e, -e, -e, -e };
                acc[nt] = iv;
            }
        }
        __syncthreads();   // drains vmcnt (kt+1 landed for ALL waves) + buffer WAR safety
    }

    // ---------------- exact recheck (bit-identical fp32 chain) ----------------
    float* zx = (float*)uni;                 // [32 dd][68] fp32 chunk; zs/es are dead
    const int pt = tid & 63;
    const int s0 = tid >> 6;                 // 4 slot-threads per point
    unsigned int nc = cntS[pt]; if (nc > 16u) nc = 16u;
    bool  act[4]; int kE[4]; float accE[4];
#pragma unroll
    for (int j = 0; j < 4; ++j) {
        unsigned int s = (unsigned int)s0 + 4u * j;
        act[j] = s < nc;
        kE[j] = act[j] ? cl[pt * 16 + s] : 0;
        accE[j] = 0.0f;
    }
#pragma unroll 1
    for (int dt = 0; dt < 8; ++dt) {
        const int dbase = dt * 32;
        __syncthreads();
        {
            int q = tid & 15, dd0 = tid >> 4;
            float4 v0 = *(const float4*)(z + zb + ((dbase + dd0) << 10) + 4 * q);
            float4 v1 = *(const float4*)(z + zb + ((dbase + dd0 + 16) << 10) + 4 * q);
            *(float4*)(zx + dd0 * 68 + 4 * q) = v0;
            *(float4*)(zx + (dd0 + 16) * 68 + 4 * q) = v1;
        }
        __syncthreads();
#pragma unroll
        for (int j = 0; j < 4; ++j) {
            if (!act[j]) continue;
            const float* er = emb + kE[j] * 256 + dbase;
            float ev[32];
#pragma unroll
            for (int c = 0; c < 8; ++c) *(float4*)(ev + 4 * c) = *(const float4*)(er + 4 * c);
            float a = accE[j];
#pragma unroll
            for (int dd = 0; dd < 32; ++dd)
                a = __builtin_fmaf(zx[dd * 68 + pt], ev[dd], a);
            accE[j] = a;
        }
    }
#pragma unroll
    for (int j = 0; j < 4; ++j) {
        if (!act[j]) continue;
        int k = kE[j];
        float t1 = __fadd_rn(z2S[pt], e2w[k]);
        float d  = __fsub_rn(t1, __fmul_rn(2.0f, accE[j]));
        atomicMin(&bestG[n0 + pt], pack_vi(d, k));
    }
    __syncthreads();

    if (ovfS) {   // near-impossible fallback: full exact scan of this quarter for overflowed pts
        for (int row = 0; row < 64; ++row) {
            if (cntS[row] <= 16u) continue;
            float fa = 0.0f;
            for (int dt = 0; dt < 8; ++dt) {
                const int dbase = dt * 32;
                __syncthreads();
                {
                    int q = tid & 15, dd0 = tid >> 4;
                    float4 v0 = *(const float4*)(z + zb + ((dbase + dd0) << 10) + 4 * q);
                    float4 v1 = *(const float4*)(z + zb + ((dbase + dd0 + 16) << 10) + 4 * q);
                    *(float4*)(zx + dd0 * 68 + 4 * q) = v0;
                    *(float4*)(zx + (dd0 + 16) * 68 + 4 * q) = v1;
                }
                __syncthreads();
                const float* er = emb + ((kq << 8) + tid) * 256 + dbase;
                for (int dd = 0; dd < 32; ++dd)
                    fa = __builtin_fmaf(zx[dd * 68 + row], er[dd], fa);
            }
            int k = (kq << 8) + tid;
            float t1 = __fadd_rn(z2S[row], e2w[k]);
            float d  = __fsub_rn(t1, __fmul_rn(2.0f, fa));
            atomicMin(&bestG[n0 + row], pack_vi(d, k));
            __syncthreads();
        }
    }
}

// 512 blocks: each block 64 points, d split in quarters across the four waves.
__global__ __launch_bounds__(256) void zq_loss_kernel(
    const float* __restrict__ z, const float* __restrict__ emb,
    const u64* __restrict__ bestG, float* __restrict__ zq,
    double* __restrict__ loss_acc, unsigned int* __restrict__ ticket,
    float* __restrict__ out_loss, float* __restrict__ out_idx)
{
    const int tl = threadIdx.x & 63;
    const int q  = threadIdx.x >> 6;         // d-quarter 0..3
    const int n  = blockIdx.x * 64 + tl;
    const int kk = (int)(u32)(bestG[n] & 0xFFFFFFFFULL);
    if (q == 0) out_idx[n] = (float)kk;
    const float* er = emb + kk * DIM + (q << 6);
    const int zb2 = z_base(n) + (q << 16);   // + (q*64)<<10
    double s = 0.0;
#pragma unroll 8
    for (int dd = 0; dd < 64; ++dd) {
        float ev = er[dd];
        float zv = z[zb2 + (dd << 10)];
        zq[zb2 + (dd << 10)] = ev;
        float df = ev - zv;
        s = fma((double)df, (double)df, s);
    }
    for (int off = 32; off; off >>= 1) s += __shfl_down(s, off, 64);
    __shared__ double sred[4];
    if ((threadIdx.x & 63) == 0) sred[threadIdx.x >> 6] = s;
    __syncthreads();
    if (threadIdx.x == 0) {
        atomicAdd(loss_acc, (sred[0] + sred[1]) + (sred[2] + sred[3]));
        __threadfence();
        unsigned int old = atomicAdd(ticket, 1u);
        if (old == gridDim.x - 1) {
            double total = atomicAdd(loss_acc, 0.0);
            out_loss[0] = (float)(1.25 * (total / 8388608.0));
        }
    }
}

extern "C" void kernel_launch(void* const* d_in, const int* in_sizes, int n_in,
                              void* d_out, int out_size, void* d_ws, size_t ws_size,
                              hipStream_t stream) {
    const float* z   = (const float*)d_in[0];
    const float* emb = (const float*)d_in[1];
    float* out = (float*)d_out;

    // ws: z2[32768]f32 @0 | eps[32768]f32 @131072 | e2[1024] @262144 |
    //     e2h[1024] @266240 | ebf16(kt-tiled image) @270336 (512KB) |
    //     loss f64 @794624 | ticket @794632 | bestG u64[32768] @794640
    float* z2w = (float*)d_ws;
    float* epsw = (float*)((char*)d_ws + 131072);
    float* e2w = (float*)((char*)d_ws + 262144);
    float* e2hw = (float*)((char*)d_ws + 266240);
    ushort_t* ebf = (ushort_t*)((char*)d_ws + 270336);
    double* loss_acc = (double*)((char*)d_ws + 794624);
    unsigned int* ticket = (unsigned int*)((char*)d_ws + 794632);
    u64* bestG = (u64*)((char*)d_ws + 794640);

    setup_kernel<<<144, 256, 0, stream>>>(z, emb, z2w, epsw, e2w, e2hw, ebf,
                                          bestG, loss_acc, ticket);
    dist_kernel<<<(NPTS / 64) * 4, 256, 0, stream>>>(z, emb, ebf, z2w, e2w, e2hw,
                                                     epsw, bestG);
    zq_loss_kernel<<<NPTS / 64, 256, 0, stream>>>(z, emb, bestG, out + ZQ_OFF,
                                                  loss_acc, ticket,
                                                  out + LOSS_OFF, out + IDX_OFF);
}